// Round 1
// baseline (523.485 us; speedup 1.0000x reference)
//
#include <hip/hip_runtime.h>

// CubeSpherePadding2D, p=1.
// Input:  [16, 64, 6, 96, 96] fp32  (BC=1024 combined batch*channel)
// Output: [16, 64, 6, 98, 98] fp32
//
// The reference's 24 sequential halo assignments are resolved analytically so
// every output element is a direct gather from the ORIGINAL input:
//  - interior: identity copy
//  - 24 face-edges: affine map (sf, br+kr*t, bc+kc*t), t = position along edge
//  - corners: faces 0-3 all zero; faces 4/5 have 8 nonzero corners that come
//    from reading already-stitched halos of faces 0-2 (traced by hand).

#define BC_TOTAL 1024
#define NF 6
#define HH 96
#define HP 98
#define IN_FACE (HH * HH)     // 9216
#define OUT_FACE (HP * HP)    // 9604
#define NOUT (BC_TOTAL * NF * OUT_FACE)  // 59,006,976

// edge_tab[f*4 + edge] = {sf, br, kr, bc, kc}
// edge: 0=top(R==0), 1=bottom(R==97), 2=left(C==0), 3=right(C==97)
// t = C-1 for top/bottom, R-1 for left/right; src = I[sf][br+kr*t][bc+kc*t]
__constant__ short edge_tab[24][5] = {
    // face 0
    {4, 95, 0, 0, 1},   // top:    I4[95][t]
    {5, 0, 0, 0, 1},    // bottom: I5[0][t]
    {3, 0, 1, 95, 0},   // left:   I3[t][95]
    {1, 0, 1, 0, 0},    // right:  I1[t][0]
    // face 1
    {4, 95, -1, 95, 0}, // top:    I4[95-t][95]
    {5, 0, 1, 95, 0},   // bottom: I5[t][95]
    {0, 0, 1, 95, 0},   // left:   I0[t][95]
    {2, 0, 1, 0, 0},    // right:  I2[t][0]
    // face 2
    {4, 0, 0, 95, -1},  // top:    I4[0][95-t]
    {5, 95, 0, 95, -1}, // bottom: I5[95][95-t]
    {1, 0, 1, 95, 0},   // left:   I1[t][95]
    {3, 0, 1, 0, 0},    // right:  I3[t][0]
    // face 3
    {4, 0, 1, 0, 0},    // top:    I4[t][0]
    {5, 95, -1, 0, 0},  // bottom: I5[95-t][0]
    {2, 0, 1, 95, 0},   // left:   I2[t][95]
    {0, 0, 1, 0, 0},    // right:  I0[t][0]
    // face 4
    {2, 0, 0, 95, -1},  // top:    I2[0][95-t]
    {0, 0, 0, 0, 1},    // bottom: I0[0][t]
    {3, 0, 0, 0, 1},    // left:   I3[0][t]
    {1, 0, 0, 95, -1},  // right:  I1[0][95-t]
    // face 5
    {0, 95, 0, 0, 1},   // top:    I0[95][t]
    {2, 95, 0, 95, -1}, // bottom: I2[95][95-t]
    {3, 95, 0, 95, -1}, // left:   I3[95][95-t]
    {1, 95, 0, 0, 1},   // right:  I1[95][t]
};

// corner_tab[(f-4)*4 + cid] = {sf, sr, sc}; cid = (R==97)*2 + (C==97)
__constant__ short corner_tab[8][3] = {
    // face 4
    {3, 0, 0},    // (0,0)   = I3[0][0]
    {1, 0, 95},   // (0,97)  = I1[0][95]
    {3, 0, 95},   // (97,0)  = I3[0][95]
    {1, 0, 0},    // (97,97) = I1[0][0]
    // face 5
    {3, 95, 95},  // (0,0)   = I3[95][95]
    {1, 95, 0},   // (0,97)  = I1[95][0]
    {3, 95, 0},   // (97,0)  = I3[95][0]
    {1, 95, 95},  // (97,97) = I1[95][95]
};

__global__ __launch_bounds__(256) void cube_pad_kernel(
    const float* __restrict__ in, float* __restrict__ out) {
    unsigned idx = blockIdx.x * 256u + threadIdx.x;
    if (idx >= (unsigned)NOUT) return;

    unsigned C  = idx % HP;
    unsigned t1 = idx / HP;
    unsigned R  = t1 % HP;
    unsigned t2 = t1 / HP;          // = bc*6 + f
    unsigned f  = t2 % NF;

    const float* fin  = in + (size_t)t2 * IN_FACE;        // this face
    const float* bcin = in + (size_t)(t2 - f) * IN_FACE;  // face 0 of this bc

    unsigned r = R - 1u;  // wraps for R==0
    unsigned c = C - 1u;
    bool rIn = r < (unsigned)HH;
    bool cIn = c < (unsigned)HH;

    float v;
    if (rIn & cIn) {
        // interior: plain copy
        v = fin[r * HH + c];
    } else if (rIn ^ cIn) {
        // edge (non-corner)
        int edge, t;
        if (!rIn) { edge = (R == 0u) ? 0 : 1; t = (int)c; }
        else      { edge = (C == 0u) ? 2 : 3; t = (int)r; }
        const short* e = edge_tab[f * 4 + edge];
        int sf = e[0];
        int sr = (int)e[1] + (int)e[2] * t;
        int sc = (int)e[3] + (int)e[4] * t;
        v = bcin[(unsigned)sf * IN_FACE + (unsigned)sr * HH + (unsigned)sc];
    } else {
        // corner
        if (f < 4u) {
            v = 0.0f;
        } else {
            int cid = ((R == 97u) ? 2 : 0) + ((C == 97u) ? 1 : 0);
            const short* e = corner_tab[(f - 4u) * 4 + cid];
            v = bcin[(unsigned)e[0] * IN_FACE + (unsigned)e[1] * HH + (unsigned)e[2]];
        }
    }
    out[idx] = v;
}

extern "C" void kernel_launch(void* const* d_in, const int* in_sizes, int n_in,
                              void* d_out, int out_size, void* d_ws, size_t ws_size,
                              hipStream_t stream) {
    const float* in = (const float*)d_in[0];
    float* out = (float*)d_out;
    unsigned nblocks = ((unsigned)NOUT + 255u) / 256u;
    hipLaunchKernelGGL(cube_pad_kernel, dim3(nblocks), dim3(256), 0, stream,
                       in, out);
}

// Round 2
// 454.494 us; speedup vs baseline: 1.1518x; 1.1518x over previous
//
#include <hip/hip_runtime.h>

// CubeSpherePadding2D, p=1.  Input [16,64,6,96,96] f32 -> output [16,64,6,98,98].
// Round 2: split into (a) vectorized branch-free interior copy (float4-aligned
// loads from input), (b) tiny gather kernel for the 388 halo elems per face.

#define BC_TOTAL 1024
#define NF 6
#define HH 96
#define HP 98
#define IN_FACE (HH * HH)     // 9216
#define OUT_FACE (HP * HP)    // 9604
#define NFACES (BC_TOTAL * NF)                 // 6144
#define NIN4 (NFACES * IN_FACE / 4)            // 14,155,776 float4 groups
#define EDGE_PER_FACE (2 * HP + 2 * HH)        // 388
#define NEDGE (NFACES * EDGE_PER_FACE)         // 2,383,872

// ---------------- interior: aligned float4 load, 4 scalar stores ----------
__global__ __launch_bounds__(256) void interior_kernel(
    const float* __restrict__ in, float* __restrict__ out) {
    unsigned i4 = blockIdx.x * 256u + threadIdx.x;   // < NIN4 exactly
    unsigned in_idx = i4 * 4u;

    unsigned c  = in_idx % HH;            // multiple of 4, same row for all 4
    unsigned rowid = in_idx / HH;
    unsigned r  = rowid % HH;
    unsigned t2 = rowid / HH;             // face index (bc*6 + f)

    float4 v = *(const float4*)(in + in_idx);   // 16B aligned

    unsigned obase = t2 * OUT_FACE + (r + 1u) * HP + (c + 1u);
    out[obase + 0u] = v.x;
    out[obase + 1u] = v.y;
    out[obase + 2u] = v.z;
    out[obase + 3u] = v.w;
}

// ---------------- edges + corners: gather from original input -------------
// edge_tab[f*4 + edge] = {sf, br, kr, bc, kc}
// edge: 0=top(R==0), 1=bottom(R==97), 2=left(C==0), 3=right(C==97)
// t = C-1 for top/bottom, R-1 for left/right; src = I[sf][br+kr*t][bc+kc*t]
__constant__ short edge_tab[24][5] = {
    {4, 95, 0, 0, 1},  {5, 0, 0, 0, 1},   {3, 0, 1, 95, 0},  {1, 0, 1, 0, 0},
    {4, 95, -1, 95, 0},{5, 0, 1, 95, 0},  {0, 0, 1, 95, 0},  {2, 0, 1, 0, 0},
    {4, 0, 0, 95, -1}, {5, 95, 0, 95, -1},{1, 0, 1, 95, 0},  {3, 0, 1, 0, 0},
    {4, 0, 1, 0, 0},   {5, 95, -1, 0, 0}, {2, 0, 1, 95, 0},  {0, 0, 1, 0, 0},
    {2, 0, 0, 95, -1}, {0, 0, 0, 0, 1},   {3, 0, 0, 0, 1},   {1, 0, 0, 95, -1},
    {0, 95, 0, 0, 1},  {2, 95, 0, 95, -1},{3, 95, 0, 95, -1},{1, 95, 0, 0, 1},
};

// corner_tab[(f-4)*4 + cid] = {sf, sr, sc}; cid = (R==97)*2 + (C==97)
__constant__ short corner_tab[8][3] = {
    {3, 0, 0},  {1, 0, 95},  {3, 0, 95},  {1, 0, 0},
    {3, 95, 95},{1, 95, 0},  {3, 95, 0},  {1, 95, 95},
};

__global__ __launch_bounds__(256) void edge_kernel(
    const float* __restrict__ in, float* __restrict__ out) {
    unsigned idx = blockIdx.x * 256u + threadIdx.x;   // < NEDGE exactly

    unsigned e  = idx % EDGE_PER_FACE;
    unsigned t2 = idx / EDGE_PER_FACE;
    unsigned f  = t2 % NF;

    // e -> (R, C) on the halo ring
    unsigned R, C;
    if (e < (unsigned)HP)            { R = 0u;       C = e; }
    else if (e < 2u * HP)            { R = 97u;      C = e - HP; }
    else if (e < 2u * HP + HH)       { C = 0u;       R = e - 2u * HP + 1u; }
    else                             { C = 97u;      R = e - (2u * HP + HH) + 1u; }

    const float* bcin = in + (size_t)(t2 - f) * IN_FACE;  // face 0 of this bc

    unsigned r = R - 1u;   // wraps for R==0
    unsigned c = C - 1u;
    bool rIn = r < (unsigned)HH;
    bool cIn = c < (unsigned)HH;

    float v;
    if (rIn ^ cIn) {
        // edge (non-corner)
        int edge, t;
        if (!rIn) { edge = (R == 0u) ? 0 : 1; t = (int)c; }
        else      { edge = (C == 0u) ? 2 : 3; t = (int)r; }
        const short* ed = edge_tab[f * 4 + edge];
        int sr = (int)ed[1] + (int)ed[2] * t;
        int sc = (int)ed[3] + (int)ed[4] * t;
        v = bcin[(unsigned)ed[0] * IN_FACE + (unsigned)sr * HH + (unsigned)sc];
    } else {
        // corner
        if (f < 4u) {
            v = 0.0f;
        } else {
            int cid = ((R == 97u) ? 2 : 0) + ((C == 97u) ? 1 : 0);
            const short* ed = corner_tab[(f - 4u) * 4 + cid];
            v = bcin[(unsigned)ed[0] * IN_FACE + (unsigned)ed[1] * HH + (unsigned)ed[2]];
        }
    }
    out[t2 * OUT_FACE + R * HP + C] = v;
}

extern "C" void kernel_launch(void* const* d_in, const int* in_sizes, int n_in,
                              void* d_out, int out_size, void* d_ws, size_t ws_size,
                              hipStream_t stream) {
    const float* in = (const float*)d_in[0];
    float* out = (float*)d_out;

    // interior: NIN4 = 14,155,776 threads, divisible by 256 (55,296 blocks)
    hipLaunchKernelGGL(interior_kernel, dim3(NIN4 / 256), dim3(256), 0, stream,
                       in, out);
    // edges: NEDGE = 2,383,872 threads, divisible by 256 (9,312 blocks)
    hipLaunchKernelGGL(edge_kernel, dim3(NEDGE / 256), dim3(256), 0, stream,
                       in, out);
}